// Round 16
// baseline (411.151 us; speedup 1.0000x reference)
//
#include <hip/hip_runtime.h>

typedef _Float16 f16;
typedef _Float16 f16x8 __attribute__((ext_vector_type(8)));
typedef float f32x4 __attribute__((ext_vector_type(4)));

#define N_ATOMS 50000
#define NEIGH   12
#define NEDGE   (N_ATOMS * NEIGH)
#define NCRYS   500
#define NBLK    196  // ceil(50000/256)

__device__ __forceinline__ void gld_lds16(const void* g, void* l) {
  __builtin_amdgcn_global_load_lds(
      (const __attribute__((address_space(1))) unsigned int*)g,
      (__attribute__((address_space(3))) unsigned int*)l, 16, 0, 0);
}

// gemm1: 3-deep pipeline, BM=128 x BN=256 (merged W-halves -> exp computed ONCE)
typedef f16 As1T[3][4][128][8];  // 24 KB
typedef f16 Bs1T[3][4][256][8];  // 48 KB
// gemmL keeps BM=256 x BN=128
typedef f16 AsLT[3][4][256][8];  // 48 KB
typedef f16 BsLT[3][4][128][8];  // 24 KB

#define WAITVM(vm)                                                        \
  asm volatile("s_waitcnt vmcnt(" #vm ") lgkmcnt(0)" ::: "memory");       \
  __builtin_amdgcn_sched_barrier(0);                                      \
  __builtin_amdgcn_s_barrier();                                           \
  __builtin_amdgcn_sched_barrier(0)

#define ENDBAR                                                            \
  __builtin_amdgcn_sched_barrier(0);                                      \
  __builtin_amdgcn_s_barrier()

// ---------------- layer-1 GEMM body ----------------
// BM=128 rows/block, BN=256 = [P|Q] in one block: exp per (row,k) computed
// exactly once (R15 PMC: VALUBusy 29% with HALF of it duplicated exp across
// the old y-split). 8 waves: wr=wid>>2 (64-row strip), wc=wid&3 (64-col strip,
// wc<2 -> P, wc>=2 -> Q). Counted-vmcnt pipeline (R14) + exp-recurrence (R15).
// Per-stage vm ops: 2 gld_lds(B) + 1 d-load (consumed next iter) -> WAITVM(3).
// MODE 1: bond [N][12], K=480 (40 filters). MODE 2: angle [N][144], K=1152.
template <int MODE, int K>
__device__ __forceinline__ void gemm1_body(
    const float* __restrict__ Asrc, const f16* __restrict__ Wcat,
    f16* __restrict__ P, f16* __restrict__ Q, int n, As1T& As, Bs1T& Bs) {
  constexpr int CIN = (MODE == 1) ? 12 : 144;
  constexpr int NT = K / 32;
  constexpr float G2I = (MODE == 1) ? 25.0f : 16.0f;  // 1/gamma^2
  constexpr float DLT = (MODE == 1) ? (8.0f / 39.0f) : (2.0f / 7.0f);
  constexpr float C1 = 2.0f * G2I * DLT;
  constexpr float C2 = G2I * DLT * DLT;
  constexpr int RUN = (MODE == 1) ? 4 : 8;  // bond 4-runs: exp(C1*u) f32 range
  const float S = __expf(-2.0f * C2);

  const int tid = threadIdx.x;
  const int lane = tid & 63;
  const int wid = tid >> 6;
  const int wr = wid >> 2;  // 0..1 (64-row strip)
  const int wc = wid & 3;   // 0..3 (64-col strip; <2 -> P, >=2 -> Q)
  const int row0 = blockIdx.x * 128;

  const int bcol = tid & 255;
  const int bkb0 = tid >> 8;  // 0..1 (+2 on pass 1)
  const int sArow = tid & 127;
  const int sAkb = (tid >> 7) & 3;  // 0..3
  int arow = row0 + sArow;
  if (arow >= n) arow = n - 1;

  f32x4 acc[4][4];
#pragma unroll
  for (int m = 0; m < 4; ++m)
#pragma unroll
    for (int q = 0; q < 4; ++q) acc[m][q] = (f32x4)0.f;

  auto daddr = [&](int t) -> const float* {
    int kg0 = t * 32 + sAkb * 8;
    int jn = (MODE == 1) ? kg0 / 40 : (kg0 >> 3);
    return &Asrc[(size_t)arow * CIN + jn];
  };
  auto bload = [&](int t) {
#pragma unroll
    for (int p = 0; p < 2; ++p) {
      int kb = bkb0 + 2 * p;
      gld_lds16(Wcat + (size_t)bcol * K + t * 32 + kb * 8, &Bs[t % 3][kb][bcol][0]);
    }
  };
  auto expwrite = [&](int t, float d) {
    int kg0 = t * 32 + sAkb * 8;
    int kk0;
    if constexpr (MODE == 1) {
      int jn = kg0 / 40;  // 40 % 8 == 0: 8-block never crosses a filter group
      kk0 = kg0 - jn * 40;
    } else {
      kk0 = 0;
    }
    f16 v[8];
#pragma unroll
    for (int h = 0; h < 8 / RUN; ++h) {
      float f0 = (float)(kk0 + h * RUN) * DLT + (MODE == 2 ? -1.0f : 0.0f);
      float u = d - f0;
      float g = __expf(-G2I * u * u);
      float ratio = __expf(C1 * u - C2);
      v[h * RUN] = (f16)g;
#pragma unroll
      for (int j = 1; j < RUN; ++j) {
        g *= ratio;
        ratio *= S;
        v[h * RUN + j] = (f16)g;
      }
    }
    *(f16x8*)&As[t % 3][sAkb][sArow][0] = *(const f16x8*)v;
  };

  float dA, dB;
  // prologue: B(0),B(1) in flight; d(2) prefetched; tiles 0,1 exp inline
  bload(0);
  bload(1);
  dA = *daddr(2);
  {
    float d0 = *daddr(0);
    expwrite(0, d0);
    float d1 = *daddr(1);
    expwrite(1, d1);
  }

  for (int t = 0; t < NT; ++t) {
    if (t + 2 < NT) bload(t + 2);
    if (t + 3 < NT) dB = *daddr(t + 3);
    if (t + 2 < NT) expwrite(t + 2, dA);  // implicit counted wait on d(t+2) only
    if (t < NT - 2) {
      WAITVM(3);  // keep B(t+2)x2 + d(t+3) in flight; B(t)/B(t+1) landed
    } else if (t == NT - 2) {
      WAITVM(2);  // only B(NT-1)x2 may remain
    } else {
      WAITVM(0);
    }
    const int buf = t % 3;
    const int kb = lane >> 4;
    const int r16 = lane & 15;
    f16x8 a[4], b[4];
#pragma unroll
    for (int m = 0; m < 4; ++m)
      a[m] = *(const f16x8*)&As[buf][kb][wr * 64 + m * 16 + r16][0];
#pragma unroll
    for (int q = 0; q < 4; ++q)
      b[q] = *(const f16x8*)&Bs[buf][kb][wc * 64 + q * 16 + r16][0];
#pragma unroll
    for (int m = 0; m < 4; ++m)
#pragma unroll
      for (int q = 0; q < 4; ++q)
        acc[m][q] =
            __builtin_amdgcn_mfma_f32_16x16x32_f16(a[m], b[q], acc[m][q], 0, 0, 0);
    ENDBAR;  // protect buf(t%3) before iter t+1 stages tile t+3 into it
    dA = dB;
  }

  const int crow = (lane >> 4) * 4;
  const int ccol = lane & 15;
  f16* outp = (wc < 2) ? P : Q;
  const int cbase = (wc & 1) * 64;
#pragma unroll
  for (int m = 0; m < 4; ++m) {
#pragma unroll
    for (int r = 0; r < 4; ++r) {
      int row = row0 + wr * 64 + m * 16 + crow + r;
      if (row < n) {
#pragma unroll
        for (int q = 0; q < 4; ++q)
          outp[(size_t)row * 128 + cbase + q * 16 + ccol] = (f16)acc[m][q][r];
      }
    }
  }
}

// grid (391, 2): y = mode (0 angle K=1152, 1 bond K=480) — co-resident.
__global__ __launch_bounds__(512) void gemm1all(
    const float* __restrict__ angle, const f16* __restrict__ Wa,
    f16* __restrict__ Pa, f16* __restrict__ Qa,
    const float* __restrict__ bond, const f16* __restrict__ Wb,
    f16* __restrict__ Pb, f16* __restrict__ Qb, int n) {
  __shared__ __align__(16) As1T As;
  __shared__ __align__(16) Bs1T Bs;
  if (blockIdx.y == 0)
    gemm1_body<2, 1152>(angle, Wa, Pa, Qa, n, As, Bs);
  else
    gemm1_body<1, 480>(bond, Wb, Pb, Qb, n, As, Bs);
}

// ---------------- layers 2-3: x' = relu([agg|x] @ Wcat2^T + b) ----------------
// BM=256, BN=128, 512 threads, IN-PLACE ax update (block-local safe).
// Per-stage vm ops: 3 gld_lds -> counted vmcnt 6/3/0.
__global__ __launch_bounds__(512) void gemmL(
    f16* __restrict__ axb, f16* __restrict__ axa, const f16* __restrict__ Wall,
    const float* __restrict__ bb, const float* __restrict__ ba, int lidx, int n) {
  __shared__ __align__(16) AsLT As;
  __shared__ __align__(16) BsLT Bs;
  const int path = blockIdx.y;
  f16* ax = path ? axa : axb;
  const f16* W = Wall + (size_t)(path * 2 + lidx) * 32768;
  const float* bias = (path ? ba : bb) + lidx * 128;

  const int tid = threadIdx.x;
  const int lane = tid & 63;
  const int wid = tid >> 6;
  const int wr = wid >> 1;  // 0..3
  const int wc = wid & 1;   // 0..1
  const int row0 = blockIdx.x * 256;

  const int bcol = tid & 127;
  const int bkb = tid >> 7;  // 0..3
  const int sArow = tid & 255;
  const int sAkb0 = tid >> 8;  // 0..1
  int arow = row0 + sArow;
  if (arow >= n) arow = n - 1;

  f32x4 acc[4][4];
#pragma unroll
  for (int m = 0; m < 4; ++m)
#pragma unroll
    for (int q = 0; q < 4; ++q) acc[m][q] = (f32x4)0.f;

  auto stage = [&](int buf, int t) {
    int k0 = t * 32;
    gld_lds16(W + (size_t)bcol * 256 + k0 + bkb * 8, &Bs[buf][bkb][bcol][0]);
#pragma unroll
    for (int p = 0; p < 2; ++p) {
      int kb = sAkb0 + 2 * p;
      gld_lds16(ax + (size_t)arow * 256 + k0 + kb * 8, &As[buf][kb][sArow][0]);
    }
  };

  stage(0, 0);
  stage(1, 1);
  for (int t = 0; t < 8; ++t) {
    if (t + 2 < 8) stage((t + 2) % 3, t + 2);
    if (t < 6) {
      WAITVM(6);
    } else if (t == 6) {
      WAITVM(3);
    } else {
      WAITVM(0);
    }
    const int buf = t % 3;
    const int kb = lane >> 4;
    const int r16 = lane & 15;
    f16x8 a[4], b[4];
#pragma unroll
    for (int m = 0; m < 4; ++m)
      a[m] = *(const f16x8*)&As[buf][kb][wr * 64 + m * 16 + r16][0];
#pragma unroll
    for (int q = 0; q < 4; ++q)
      b[q] = *(const f16x8*)&Bs[buf][kb][wc * 64 + q * 16 + r16][0];
#pragma unroll
    for (int m = 0; m < 4; ++m)
#pragma unroll
      for (int q = 0; q < 4; ++q)
        acc[m][q] =
            __builtin_amdgcn_mfma_f32_16x16x32_f16(a[m], b[q], acc[m][q], 0, 0, 0);
    ENDBAR;
  }

  const int crow = (lane >> 4) * 4;
  const int ccol = lane & 15;
#pragma unroll
  for (int m = 0; m < 4; ++m) {
#pragma unroll
    for (int r = 0; r < 4; ++r) {
      int row = row0 + wr * 64 + m * 16 + crow + r;
      if (row < n) {
#pragma unroll
        for (int q = 0; q < 4; ++q) {
          int col = wc * 64 + q * 16 + ccol;
          float v = acc[m][q][r] + bias[col];
          ax[(size_t)row * 256 + 128 + col] = (f16)fmaxf(v, 0.0f);
        }
      }
    }
  }
}

// ---------------- weight conversion ----------------
__global__ void cvtW(const float* __restrict__ Wl, const float* __restrict__ Wr,
                     f16* __restrict__ outp, int K) {
  int c = blockIdx.y;
  int k = blockIdx.x * 256 + threadIdx.x;
  if (k < K)
    outp[(size_t)c * K + k] =
        (f16)((c < 128) ? Wl[(size_t)c * K + k] : Wr[(size_t)(c - 128) * K + k]);
}

__global__ void cvtW_small(const float* __restrict__ Wl_b, const float* __restrict__ Wr_b,
                           const float* __restrict__ Wl_a, const float* __restrict__ Wr_a,
                           f16* __restrict__ outp) {
  int idx = blockIdx.x * 256 + threadIdx.x;  // 4*128*256
  int l = idx >> 15;
  int c = (idx >> 8) & 127;
  int k = idx & 255;
  const float* Wl = (l < 2) ? Wl_b + (size_t)l * 16384 : Wl_a + (size_t)(l - 2) * 16384;
  const float* Wr = (l < 2) ? Wr_b + (size_t)l * 16384 : Wr_a + (size_t)(l - 2) * 16384;
  float v = (k < 128) ? Wl[(size_t)c * 128 + k] : Wr[(size_t)c * 128 + (k - 128)];
  outp[idx] = (f16)v;
}

// ---------------- CSR build ----------------
__global__ void k_count(const int* __restrict__ nbr, int* __restrict__ deg) {
  int e = blockIdx.x * 256 + threadIdx.x;
  if (e < NEDGE) atomicAdd(&deg[nbr[e]], 1);
}
__global__ void k_scan1(const int* __restrict__ deg, int* __restrict__ rowptr,
                        int* __restrict__ bsum) {
  __shared__ int s[256];
  int t = threadIdx.x, i = blockIdx.x * 256 + t;
  int v = (i < N_ATOMS) ? deg[i] : 0;
  s[t] = v;
  __syncthreads();
  for (int off = 1; off < 256; off <<= 1) {
    int x = (t >= off) ? s[t - off] : 0;
    __syncthreads();
    s[t] += x;
    __syncthreads();
  }
  if (i < N_ATOMS) rowptr[i] = s[t] - v;
  if (t == 255) bsum[blockIdx.x] = s[255];
}
__global__ void k_scan2(int* __restrict__ bsum) {
  __shared__ int s[256];
  int t = threadIdx.x;
  int v = (t < NBLK) ? bsum[t] : 0;
  s[t] = v;
  __syncthreads();
  for (int off = 1; off < 256; off <<= 1) {
    int x = (t >= off) ? s[t - off] : 0;
    __syncthreads();
    s[t] += x;
    __syncthreads();
  }
  if (t < NBLK) bsum[t] = s[t] - v;
}
__global__ void k_scan3(int* __restrict__ rowptr, const int* __restrict__ bsum) {
  int i = blockIdx.x * 256 + threadIdx.x;
  if (i < N_ATOMS) rowptr[i] += bsum[blockIdx.x];
  if (i == 0) rowptr[N_ATOMS] = NEDGE;
}
// eidx stores PRE-SCALED byte offsets (src*256) for base+zext(u32) addressing.
__global__ void k_fill(const int* __restrict__ nbr, const int* __restrict__ rowptr,
                       int* __restrict__ cursor, int* __restrict__ eidx) {
  int e = blockIdx.x * 256 + threadIdx.x;
  if (e < NEDGE) {
    int dst = nbr[e];
    int pos = rowptr[dst] + atomicAdd(&cursor[dst], 1);
    eidx[pos] = (e / NEIGH) << 8;  // src atom * 256 bytes (P row)
  }
}

// ---------------- layer-1 finalize: x = relu(mean_j P[src_j] + b + Q) ----------------
__global__ __launch_bounds__(256) void gather_fin1(
    const f16* __restrict__ Pb, const f16* __restrict__ Qb,
    const f16* __restrict__ Pa, const f16* __restrict__ Qa,
    const int* __restrict__ rowptr, const int* __restrict__ eidx,
    const float* __restrict__ bias_b, const float* __restrict__ bias_a,
    f16* __restrict__ axb, f16* __restrict__ axa) {
  const int path = blockIdx.y;
  const char* Pc = (const char*)(path ? Pa : Pb);
  const f16* Q = path ? Qa : Qb;
  const float* bias = path ? bias_a : bias_b;
  f16* ax = path ? axa : axb;
  const int t = threadIdx.x;
  const int a = blockIdx.x * 16 + (t >> 4);
  const int g = (t & 15) * 8;
  const unsigned gb = (unsigned)(t & 15) * 16;
  const int s0 = rowptr[a], s1 = rowptr[a + 1];
  float acc[8];
#pragma unroll
  for (int u = 0; u < 8; ++u) acc[u] = 0.f;
  int j = s0;
  for (; j + 8 <= s1; j += 8) {
    f16x8 v[8];
#pragma unroll
    for (int u = 0; u < 8; ++u)
      v[u] = *(const f16x8*)(Pc + (size_t)((unsigned)eidx[j + u] + gb));
    f16x8 s = ((v[0] + v[1]) + (v[2] + v[3])) + ((v[4] + v[5]) + (v[6] + v[7]));
#pragma unroll
    for (int c = 0; c < 8; ++c) acc[c] += (float)s[c];
  }
  for (; j + 4 <= s1; j += 4) {
    f16x8 v0 = *(const f16x8*)(Pc + (size_t)((unsigned)eidx[j] + gb));
    f16x8 v1 = *(const f16x8*)(Pc + (size_t)((unsigned)eidx[j + 1] + gb));
    f16x8 v2 = *(const f16x8*)(Pc + (size_t)((unsigned)eidx[j + 2] + gb));
    f16x8 v3 = *(const f16x8*)(Pc + (size_t)((unsigned)eidx[j + 3] + gb));
    f16x8 s = (v0 + v1) + (v2 + v3);
#pragma unroll
    for (int c = 0; c < 8; ++c) acc[c] += (float)s[c];
  }
  for (; j < s1; ++j) {
    f16x8 v = *(const f16x8*)(Pc + (size_t)((unsigned)eidx[j] + gb));
#pragma unroll
    for (int c = 0; c < 8; ++c) acc[c] += (float)v[c];
  }
  f16x8 q = *(const f16x8*)&Q[(size_t)a * 128 + g];
  float inv = 1.0f / fmaxf((float)(s1 - s0), 1.0f);
  f16 outv[8];
#pragma unroll
  for (int u = 0; u < 8; ++u) {
    float v = acc[u] * inv + bias[g + u] + (float)q[u];
    outv[u] = (f16)fmaxf(v, 0.0f);
  }
  *(f16x8*)&ax[(size_t)a * 256 + 128 + g] = *(const f16x8*)outv;
}

// ---------------- layers 2-3 aggregation: agg half <- mean_j x[src_j] ----------------
__global__ __launch_bounds__(256) void gather_mean(
    f16* __restrict__ axb, f16* __restrict__ axa,
    const int* __restrict__ rowptr, const int* __restrict__ eidx) {
  f16* ax = blockIdx.y ? axa : axb;
  const char* axc = (const char*)ax;
  const int t = threadIdx.x;
  const int a = blockIdx.x * 16 + (t >> 4);
  const int g = (t & 15) * 8;
  const unsigned gb = 256u + (unsigned)(t & 15) * 16;
  const int s0 = rowptr[a], s1 = rowptr[a + 1];
  float acc[8];
#pragma unroll
  for (int u = 0; u < 8; ++u) acc[u] = 0.f;
  int j = s0;
  for (; j + 8 <= s1; j += 8) {
    f16x8 v[8];
#pragma unroll
    for (int u = 0; u < 8; ++u)
      v[u] = *(const f16x8*)(axc + (size_t)(((unsigned)eidx[j + u] << 1) + gb));
    f16x8 s = ((v[0] + v[1]) + (v[2] + v[3])) + ((v[4] + v[5]) + (v[6] + v[7]));
#pragma unroll
    for (int c = 0; c < 8; ++c) acc[c] += (float)s[c];
  }
  for (; j + 4 <= s1; j += 4) {
    f16x8 v0 = *(const f16x8*)(axc + (size_t)(((unsigned)eidx[j] << 1) + gb));
    f16x8 v1 = *(const f16x8*)(axc + (size_t)(((unsigned)eidx[j + 1] << 1) + gb));
    f16x8 v2 = *(const f16x8*)(axc + (size_t)(((unsigned)eidx[j + 2] << 1) + gb));
    f16x8 v3 = *(const f16x8*)(axc + (size_t)(((unsigned)eidx[j + 3] << 1) + gb));
    f16x8 s = (v0 + v1) + (v2 + v3);
#pragma unroll
    for (int c = 0; c < 8; ++c) acc[c] += (float)s[c];
  }
  for (; j < s1; ++j) {
    f16x8 v = *(const f16x8*)(axc + (size_t)(((unsigned)eidx[j] << 1) + gb));
#pragma unroll
    for (int c = 0; c < 8; ++c) acc[c] += (float)v[c];
  }
  float inv = 1.0f / fmaxf((float)(s1 - s0), 1.0f);
  f16 outv[8];
#pragma unroll
  for (int u = 0; u < 8; ++u) outv[u] = (f16)(acc[u] * inv);
  *(f16x8*)&ax[(size_t)a * 256 + g] = *(const f16x8*)outv;
}

// ---------------- head: pool -> mlp -> mlp -> fc ----------------
__global__ __launch_bounds__(256) void head_kernel(
    const f16* __restrict__ axb, const f16* __restrict__ axa,
    const int* __restrict__ crys, const float* __restrict__ W_mlp,
    const float* __restrict__ b_mlp, const float* __restrict__ W_fc,
    const float* __restrict__ b_fc, float* __restrict__ outp) {
  __shared__ float sh0[256], sh1[256];
  const int cry = blockIdx.x, c = threadIdx.x;
  const int s = crys[2 * cry], e = crys[2 * cry + 1];
  const f16* src = (c < 128) ? axb : axa;
  const int ch = c & 127;
  float sum = 0.f;
  for (int r = s; r < e; ++r) sum += (float)src[(size_t)r * 256 + 128 + ch];
  sh0[c] = sum / fmaxf((float)(e - s), 1.0f);
  __syncthreads();
  {
    const float* wrow = W_mlp + (size_t)c * 256;
    float s2 = b_mlp[c];
#pragma unroll 8
    for (int k = 0; k < 256; k += 4) {
      float4 w = *(const float4*)&wrow[k];
      s2 += sh0[k] * w.x + sh0[k + 1] * w.y + sh0[k + 2] * w.z + sh0[k + 3] * w.w;
    }
    sh1[c] = s2;
  }
  __syncthreads();
  {
    const float* wrow = W_mlp + 65536 + (size_t)c * 256;
    float s2 = b_mlp[256 + c];
#pragma unroll 8
    for (int k = 0; k < 256; k += 4) {
      float4 w = *(const float4*)&wrow[k];
      s2 += sh1[k] * w.x + sh1[k + 1] * w.y + sh1[k + 2] * w.z + sh1[k + 3] * w.w;
    }
    sh0[c] = s2;
  }
  __syncthreads();
  if (c < 2) {
    const float* wrow = W_fc + c * 256;
    float s2 = b_fc[c];
    for (int k = 0; k < 256; ++k) s2 += sh0[k] * wrow[k];
    outp[cry * 2 + c] = s2;
  }
}

extern "C" void kernel_launch(void* const* d_in, const int* in_sizes, int n_in,
                              void* d_out, int out_size, void* d_ws, size_t ws_size,
                              hipStream_t stream) {
  const float* bond  = (const float*)d_in[0];
  const float* angle = (const float*)d_in[1];
  const int*   nbr   = (const int*)d_in[3];
  const int*   crys  = (const int*)d_in[4];
  const float* Wl_b1 = (const float*)d_in[5];
  const float* Wr_b1 = (const float*)d_in[6];
  const float* b_b1  = (const float*)d_in[7];
  const float* Wl_a1 = (const float*)d_in[8];
  const float* Wr_a1 = (const float*)d_in[9];
  const float* b_a1  = (const float*)d_in[10];
  const float* Wl_b  = (const float*)d_in[11];
  const float* Wr_b  = (const float*)d_in[12];
  const float* b_b   = (const float*)d_in[13];
  const float* Wl_a  = (const float*)d_in[14];
  const float* Wr_a  = (const float*)d_in[15];
  const float* b_a   = (const float*)d_in[16];
  const float* W_mlp = (const float*)d_in[17];
  const float* b_mlp = (const float*)d_in[18];
  const float* W_fc  = (const float*)d_in[19];
  const float* b_fc  = (const float*)d_in[20];

  char* w = (char*)d_ws;
  auto alloc = [&](size_t bytes) {
    void* p = (void*)w;
    w += (bytes + 255) & ~(size_t)255;
    return p;
  };
  f16* axb = (f16*)alloc((size_t)N_ATOMS * 256 * 2);
  f16* axa = (f16*)alloc((size_t)N_ATOMS * 256 * 2);
  f16* Pb  = (f16*)alloc((size_t)N_ATOMS * 128 * 2);
  f16* Qb  = (f16*)alloc((size_t)N_ATOMS * 128 * 2);
  f16* Pa  = (f16*)alloc((size_t)N_ATOMS * 128 * 2);
  f16* Qa  = (f16*)alloc((size_t)N_ATOMS * 128 * 2);
  f16* Wb1c = (f16*)alloc((size_t)256 * 480 * 2);
  f16* Wa1c = (f16*)alloc((size_t)256 * 1152 * 2);
  f16* Wsm  = (f16*)alloc((size_t)4 * 128 * 256 * 2);
  // deg+cursor as ONE contiguous block: the single memset must cover BOTH
  // (0xAA re-poison between timed replays otherwise leaves cursor garbage).
  int* deg    = (int*)alloc((size_t)2 * N_ATOMS * 4);
  int* cursor = deg + N_ATOMS;
  int* rowptr = (int*)alloc((size_t)(N_ATOMS + 1) * 4);
  int* eidx   = (int*)alloc((size_t)NEDGE * 4);
  int* bsum   = (int*)alloc(256 * 4);

  // weights -> fp16
  cvtW<<<dim3(2, 256), 256, 0, stream>>>(Wl_b1, Wr_b1, Wb1c, 480);
  cvtW<<<dim3(5, 256), 256, 0, stream>>>(Wl_a1, Wr_a1, Wa1c, 1152);
  cvtW_small<<<512, 256, 0, stream>>>(Wl_b, Wr_b, Wl_a, Wr_a, Wsm);

  // CSR build
  hipMemsetAsync(deg, 0, (size_t)2 * N_ATOMS * 4, stream);
  k_count<<<(NEDGE + 255) / 256, 256, 0, stream>>>(nbr, deg);
  k_scan1<<<NBLK, 256, 0, stream>>>(deg, rowptr, bsum);
  k_scan2<<<1, 256, 0, stream>>>(bsum);
  k_scan3<<<NBLK, 256, 0, stream>>>(rowptr, bsum);
  k_fill<<<(NEDGE + 255) / 256, 256, 0, stream>>>(nbr, rowptr, cursor, eidx);

  const int GG = (N_ATOMS + 127) / 128;  // 391 (gemm1, BM=128)
  const int GT = (N_ATOMS + 255) / 256;  // 196 (gemmL, BM=256)
  const int AG = N_ATOMS / 16;           // 3125

  // layer 1: single dispatch, merged W-halves (exp once), angle+bond via y
  gemm1all<<<dim3(GG, 2), 512, 0, stream>>>(angle, Wa1c, Pa, Qa,
                                            bond, Wb1c, Pb, Qb, N_ATOMS);
  gather_fin1<<<dim3(AG, 2), 256, 0, stream>>>(Pb, Qb, Pa, Qa, rowptr, eidx,
                                               b_b1, b_a1, axb, axa);

  // layers 2-3 (aggregate-then-project, in-place ax)
  for (int l = 0; l < 2; ++l) {
    gather_mean<<<dim3(AG, 2), 256, 0, stream>>>(axb, axa, rowptr, eidx);
    gemmL<<<dim3(GT, 2), 512, 0, stream>>>(axb, axa, Wsm, b_b, b_a, l, N_ATOMS);
  }

  // head
  head_kernel<<<NCRYS, 256, 0, stream>>>(axb, axa, crys, W_mlp, b_mlp, W_fc, b_fc,
                                         (float*)d_out);
}

// Round 17
// 389.264 us; speedup vs baseline: 1.0562x; 1.0562x over previous
//
#include <hip/hip_runtime.h>

typedef _Float16 f16;
typedef _Float16 f16x8 __attribute__((ext_vector_type(8)));
typedef float f32x4 __attribute__((ext_vector_type(4)));

#define N_ATOMS 50000
#define NEIGH   12
#define NEDGE   (N_ATOMS * NEIGH)
#define NCRYS   500
#define NBLK    196  // ceil(50000/256)

__device__ __forceinline__ void gld_lds16(const void* g, void* l) {
  __builtin_amdgcn_global_load_lds(
      (const __attribute__((address_space(1))) unsigned int*)g,
      (__attribute__((address_space(3))) unsigned int*)l, 16, 0, 0);
}

// 3-deep pipeline buffers (T3/T4 counted vmcnt across raw s_barrier).
typedef f16 AsT[3][4][256][8];  // 48 KB
typedef f16 BsT[3][4][128][8];  // 24 KB

#define WAITVM(vm)                                                        \
  asm volatile("s_waitcnt vmcnt(" #vm ") lgkmcnt(0)" ::: "memory");       \
  __builtin_amdgcn_sched_barrier(0);                                      \
  __builtin_amdgcn_s_barrier();                                           \
  __builtin_amdgcn_sched_barrier(0)

#define ENDBAR                                                            \
  __builtin_amdgcn_sched_barrier(0);                                      \
  __builtin_amdgcn_s_barrier()

// ---------------- layer-1 GEMM body (R15 config — measured best: 90us) ----------
// BM=256 rows/block, BN=128 cols; half: 0 -> Wl (P), 1 -> Wr (Q).
// d-loads issued one iteration ahead of exp consumption; GBF via exp-recurrence
// (2 exps + 14 muls per 8-run; bond 4-runs for f32 exp range).
// R16 lesson: merging W-halves (BN=256) doubles B staging -> +18us net loss;
// the y-split's duplicated exp is the cheaper side of that trade.
// MODE 1: bond [N][12], K=480 (40 filters). MODE 2: angle [N][144], K=1152.
template <int MODE, int K>
__device__ __forceinline__ void gemm1_body(
    const float* __restrict__ Asrc, const f16* __restrict__ Wcat,
    f16* __restrict__ P, f16* __restrict__ Q, int n, AsT& As, BsT& Bs) {
  constexpr int CIN = (MODE == 1) ? 12 : 144;
  constexpr int NT = K / 32;
  constexpr float G2I = (MODE == 1) ? 25.0f : 16.0f;  // 1/gamma^2
  constexpr float DLT = (MODE == 1) ? (8.0f / 39.0f) : (2.0f / 7.0f);
  constexpr float C1 = 2.0f * G2I * DLT;
  constexpr float C2 = G2I * DLT * DLT;
  constexpr int RUN = (MODE == 1) ? 4 : 8;  // bond 4-runs: exp(C1*u) f32 range
  const float S = __expf(-2.0f * C2);

  const int tid = threadIdx.x;
  const int lane = tid & 63;
  const int wid = tid >> 6;
  const int wr = wid >> 1;  // 0..3 (64-row strip)
  const int wc = wid & 1;   // 0..1 (64-col strip)
  const int row0 = blockIdx.x * 256;
  const int half = blockIdx.y;
  const f16* Wh = Wcat + (size_t)half * 128 * K;
  f16* outp = half ? Q : P;

  const int bcol = tid & 127;
  const int bkb = tid >> 7;  // 0..3
  const int sArow = tid & 255;
  const int sAkb0 = tid >> 8;  // 0..1 (+2 on pass 1)
  int arow = row0 + sArow;
  if (arow >= n) arow = n - 1;

  f32x4 acc[4][4];
#pragma unroll
  for (int m = 0; m < 4; ++m)
#pragma unroll
    for (int q = 0; q < 4; ++q) acc[m][q] = (f32x4)0.f;

  auto daddr = [&](int t, int p) -> const float* {
    int kb = sAkb0 + 2 * p;
    int kg0 = t * 32 + kb * 8;
    int jn = (MODE == 1) ? kg0 / 40 : (kg0 >> 3);
    return &Asrc[(size_t)arow * CIN + jn];
  };
  auto bload = [&](int t) {
    gld_lds16(Wh + (size_t)bcol * K + t * 32 + bkb * 8, &Bs[t % 3][bkb][bcol][0]);
  };
  auto expwrite = [&](int t, const float* d2) {
#pragma unroll
    for (int p = 0; p < 2; ++p) {
      int kb = sAkb0 + 2 * p;
      int kg0 = t * 32 + kb * 8;
      float d = d2[p];
      int kk0;
      if constexpr (MODE == 1) {
        int jn = kg0 / 40;  // 40 % 8 == 0: 8-block never crosses a filter group
        kk0 = kg0 - jn * 40;
      } else {
        kk0 = 0;
      }
      f16 v[8];
#pragma unroll
      for (int h = 0; h < 8 / RUN; ++h) {
        float f0 = (float)(kk0 + h * RUN) * DLT + (MODE == 2 ? -1.0f : 0.0f);
        float u = d - f0;
        float g = __expf(-G2I * u * u);
        float ratio = __expf(C1 * u - C2);
        v[h * RUN] = (f16)g;
#pragma unroll
        for (int j = 1; j < RUN; ++j) {
          g *= ratio;
          ratio *= S;
          v[h * RUN + j] = (f16)g;
        }
      }
      *(f16x8*)&As[t % 3][kb][sArow][0] = *(const f16x8*)v;
    }
  };

  float dA[2], dB[2];
  // prologue: B for tiles 0,1 in flight; d(2) prefetched; tiles 0,1 exp inline
  bload(0);
  bload(1);
  dA[0] = *daddr(2, 0);
  dA[1] = *daddr(2, 1);
  {
    float d0[2] = {*daddr(0, 0), *daddr(0, 1)};
    expwrite(0, d0);
    float d1[2] = {*daddr(1, 0), *daddr(1, 1)};
    expwrite(1, d1);
  }

  for (int t = 0; t < NT; ++t) {
    if (t + 2 < NT) bload(t + 2);
    if (t + 3 < NT) {
      dB[0] = *daddr(t + 3, 0);
      dB[1] = *daddr(t + 3, 1);
    }
    if (t + 2 < NT) expwrite(t + 2, dA);  // implicit counted wait on dA only
    if (t < NT - 3) {
      WAITVM(3);  // newest 3 = B(t+2), d(t+3)x2 stay in flight; B(t) is landed
    } else {
      WAITVM(0);  // tail: precise drain
    }
    const int buf = t % 3;
    const int kb = lane >> 4;
    const int r16 = lane & 15;
    f16x8 a[4], b[4];
#pragma unroll
    for (int m = 0; m < 4; ++m)
      a[m] = *(const f16x8*)&As[buf][kb][wr * 64 + m * 16 + r16][0];
#pragma unroll
    for (int q = 0; q < 4; ++q)
      b[q] = *(const f16x8*)&Bs[buf][kb][wc * 64 + q * 16 + r16][0];
#pragma unroll
    for (int m = 0; m < 4; ++m)
#pragma unroll
      for (int q = 0; q < 4; ++q)
        acc[m][q] =
            __builtin_amdgcn_mfma_f32_16x16x32_f16(a[m], b[q], acc[m][q], 0, 0, 0);
    ENDBAR;  // protect buf(t%3) from stage(t+3) next iter
    dA[0] = dB[0];
    dA[1] = dB[1];
  }

  const int crow = (lane >> 4) * 4;
  const int ccol = lane & 15;
#pragma unroll
  for (int m = 0; m < 4; ++m) {
#pragma unroll
    for (int r = 0; r < 4; ++r) {
      int row = row0 + wr * 64 + m * 16 + crow + r;
      if (row < n) {
#pragma unroll
        for (int q = 0; q < 4; ++q)
          outp[(size_t)row * 128 + wc * 64 + q * 16 + ccol] = (f16)acc[m][q][r];
      }
    }
  }
}

// grid (196, 2, 2): y = W-half, z = mode (0 angle K=1152, 1 bond K=480).
__global__ __launch_bounds__(512) void gemm1all(
    const float* __restrict__ angle, const f16* __restrict__ Wa,
    f16* __restrict__ Pa, f16* __restrict__ Qa,
    const float* __restrict__ bond, const f16* __restrict__ Wb,
    f16* __restrict__ Pb, f16* __restrict__ Qb, int n) {
  __shared__ __align__(16) AsT As;
  __shared__ __align__(16) BsT Bs;
  if (blockIdx.z == 0)
    gemm1_body<2, 1152>(angle, Wa, Pa, Qa, n, As, Bs);
  else
    gemm1_body<1, 480>(bond, Wb, Pb, Qb, n, As, Bs);
}

// ---------------- layers 2-3: x' = relu([agg|x] @ Wcat2^T + b) ----------------
// BM=256, BN=128, 512 threads, IN-PLACE ax update (block-local safe).
// Per-stage vm ops: 3 gld_lds -> counted vmcnt 6/3/0.
__global__ __launch_bounds__(512) void gemmL(
    f16* __restrict__ axb, f16* __restrict__ axa, const f16* __restrict__ Wall,
    const float* __restrict__ bb, const float* __restrict__ ba, int lidx, int n) {
  __shared__ __align__(16) AsT As;
  __shared__ __align__(16) BsT Bs;
  const int path = blockIdx.y;
  f16* ax = path ? axa : axb;
  const f16* W = Wall + (size_t)(path * 2 + lidx) * 32768;
  const float* bias = (path ? ba : bb) + lidx * 128;

  const int tid = threadIdx.x;
  const int lane = tid & 63;
  const int wid = tid >> 6;
  const int wr = wid >> 1;  // 0..3
  const int wc = wid & 1;   // 0..1
  const int row0 = blockIdx.x * 256;

  const int bcol = tid & 127;
  const int bkb = tid >> 7;  // 0..3
  const int sArow = tid & 255;
  const int sAkb0 = tid >> 8;  // 0..1
  int arow = row0 + sArow;
  if (arow >= n) arow = n - 1;

  f32x4 acc[4][4];
#pragma unroll
  for (int m = 0; m < 4; ++m)
#pragma unroll
    for (int q = 0; q < 4; ++q) acc[m][q] = (f32x4)0.f;

  auto stage = [&](int buf, int t) {
    int k0 = t * 32;
    gld_lds16(W + (size_t)bcol * 256 + k0 + bkb * 8, &Bs[buf][bkb][bcol][0]);
#pragma unroll
    for (int p = 0; p < 2; ++p) {
      int kb = sAkb0 + 2 * p;
      gld_lds16(ax + (size_t)arow * 256 + k0 + kb * 8, &As[buf][kb][sArow][0]);
    }
  };

  stage(0, 0);
  stage(1, 1);
  for (int t = 0; t < 8; ++t) {
    if (t + 2 < 8) stage((t + 2) % 3, t + 2);
    if (t < 6) {
      WAITVM(6);
    } else if (t == 6) {
      WAITVM(3);
    } else {
      WAITVM(0);
    }
    const int buf = t % 3;
    const int kb = lane >> 4;
    const int r16 = lane & 15;
    f16x8 a[4], b[4];
#pragma unroll
    for (int m = 0; m < 4; ++m)
      a[m] = *(const f16x8*)&As[buf][kb][wr * 64 + m * 16 + r16][0];
#pragma unroll
    for (int q = 0; q < 4; ++q)
      b[q] = *(const f16x8*)&Bs[buf][kb][wc * 64 + q * 16 + r16][0];
#pragma unroll
    for (int m = 0; m < 4; ++m)
#pragma unroll
      for (int q = 0; q < 4; ++q)
        acc[m][q] =
            __builtin_amdgcn_mfma_f32_16x16x32_f16(a[m], b[q], acc[m][q], 0, 0, 0);
    ENDBAR;
  }

  const int crow = (lane >> 4) * 4;
  const int ccol = lane & 15;
#pragma unroll
  for (int m = 0; m < 4; ++m) {
#pragma unroll
    for (int r = 0; r < 4; ++r) {
      int row = row0 + wr * 64 + m * 16 + crow + r;
      if (row < n) {
#pragma unroll
        for (int q = 0; q < 4; ++q) {
          int col = wc * 64 + q * 16 + ccol;
          float v = acc[m][q][r] + bias[col];
          ax[(size_t)row * 256 + 128 + col] = (f16)fmaxf(v, 0.0f);
        }
      }
    }
  }
}

// ---------------- weight conversion: ALL weights in ONE dispatch ----------------
// flat idx: [0, 256*480) -> Wb1c; [.., +256*1152) -> Wa1c; [.., +4*128*256) -> Wsm
__global__ void cvtW_all(const float* __restrict__ Wl_b1, const float* __restrict__ Wr_b1,
                         const float* __restrict__ Wl_a1, const float* __restrict__ Wr_a1,
                         const float* __restrict__ Wl_b, const float* __restrict__ Wr_b,
                         const float* __restrict__ Wl_a, const float* __restrict__ Wr_a,
                         f16* __restrict__ Wb1c, f16* __restrict__ Wa1c,
                         f16* __restrict__ Wsm) {
  int idx = blockIdx.x * 256 + threadIdx.x;
  const int N1 = 256 * 480, N2 = 256 * 1152, N3 = 4 * 128 * 256;
  if (idx < N1) {
    int c = idx / 480, k = idx - c * 480;
    Wb1c[idx] = (f16)((c < 128) ? Wl_b1[(size_t)c * 480 + k]
                                : Wr_b1[(size_t)(c - 128) * 480 + k]);
    return;
  }
  idx -= N1;
  if (idx < N2) {
    int c = idx / 1152, k = idx - c * 1152;
    Wa1c[idx] = (f16)((c < 128) ? Wl_a1[(size_t)c * 1152 + k]
                                : Wr_a1[(size_t)(c - 128) * 1152 + k]);
    return;
  }
  idx -= N2;
  if (idx < N3) {
    int l = idx >> 15;
    int c = (idx >> 8) & 127;
    int k = idx & 255;
    const float* Wl = (l < 2) ? Wl_b + (size_t)l * 16384 : Wl_a + (size_t)(l - 2) * 16384;
    const float* Wr = (l < 2) ? Wr_b + (size_t)l * 16384 : Wr_a + (size_t)(l - 2) * 16384;
    float v = (k < 128) ? Wl[(size_t)c * 128 + k] : Wr[(size_t)c * 128 + (k - 128)];
    Wsm[idx] = (f16)v;
  }
}

// ---------------- CSR build ----------------
__global__ void k_count(const int* __restrict__ nbr, int* __restrict__ deg) {
  int e = blockIdx.x * 256 + threadIdx.x;
  if (e < NEDGE) atomicAdd(&deg[nbr[e]], 1);
}
__global__ void k_scan1(const int* __restrict__ deg, int* __restrict__ rowptr,
                        int* __restrict__ bsum) {
  __shared__ int s[256];
  int t = threadIdx.x, i = blockIdx.x * 256 + t;
  int v = (i < N_ATOMS) ? deg[i] : 0;
  s[t] = v;
  __syncthreads();
  for (int off = 1; off < 256; off <<= 1) {
    int x = (t >= off) ? s[t - off] : 0;
    __syncthreads();
    s[t] += x;
    __syncthreads();
  }
  if (i < N_ATOMS) rowptr[i] = s[t] - v;
  if (t == 255) bsum[blockIdx.x] = s[255];
}
__global__ void k_scan2(int* __restrict__ bsum) {
  __shared__ int s[256];
  int t = threadIdx.x;
  int v = (t < NBLK) ? bsum[t] : 0;
  s[t] = v;
  __syncthreads();
  for (int off = 1; off < 256; off <<= 1) {
    int x = (t >= off) ? s[t - off] : 0;
    __syncthreads();
    s[t] += x;
    __syncthreads();
  }
  if (t < NBLK) bsum[t] = s[t] - v;
}
__global__ void k_scan3(int* __restrict__ rowptr, const int* __restrict__ bsum) {
  int i = blockIdx.x * 256 + threadIdx.x;
  if (i < N_ATOMS) rowptr[i] += bsum[blockIdx.x];
  if (i == 0) rowptr[N_ATOMS] = NEDGE;
}
// eidx stores PRE-SCALED byte offsets (src*256) for base+zext(u32) addressing.
__global__ void k_fill(const int* __restrict__ nbr, const int* __restrict__ rowptr,
                       int* __restrict__ cursor, int* __restrict__ eidx) {
  int e = blockIdx.x * 256 + threadIdx.x;
  if (e < NEDGE) {
    int dst = nbr[e];
    int pos = rowptr[dst] + atomicAdd(&cursor[dst], 1);
    eidx[pos] = (e / NEIGH) << 8;  // src atom * 256 bytes (P row)
  }
}

// ---------------- layer-1 finalize: x = relu(mean_j P[src_j] + b + Q) ----------------
__global__ __launch_bounds__(256) void gather_fin1(
    const f16* __restrict__ Pb, const f16* __restrict__ Qb,
    const f16* __restrict__ Pa, const f16* __restrict__ Qa,
    const int* __restrict__ rowptr, const int* __restrict__ eidx,
    const float* __restrict__ bias_b, const float* __restrict__ bias_a,
    f16* __restrict__ axb, f16* __restrict__ axa) {
  const int path = blockIdx.y;
  const char* Pc = (const char*)(path ? Pa : Pb);
  const f16* Q = path ? Qa : Qb;
  const float* bias = path ? bias_a : bias_b;
  f16* ax = path ? axa : axb;
  const int t = threadIdx.x;
  const int a = blockIdx.x * 16 + (t >> 4);
  const int g = (t & 15) * 8;
  const unsigned gb = (unsigned)(t & 15) * 16;
  const int s0 = rowptr[a], s1 = rowptr[a + 1];
  float acc[8];
#pragma unroll
  for (int u = 0; u < 8; ++u) acc[u] = 0.f;
  int j = s0;
  for (; j + 8 <= s1; j += 8) {
    f16x8 v[8];
#pragma unroll
    for (int u = 0; u < 8; ++u)
      v[u] = *(const f16x8*)(Pc + (size_t)((unsigned)eidx[j + u] + gb));
    f16x8 s = ((v[0] + v[1]) + (v[2] + v[3])) + ((v[4] + v[5]) + (v[6] + v[7]));
#pragma unroll
    for (int c = 0; c < 8; ++c) acc[c] += (float)s[c];
  }
  for (; j + 4 <= s1; j += 4) {
    f16x8 v0 = *(const f16x8*)(Pc + (size_t)((unsigned)eidx[j] + gb));
    f16x8 v1 = *(const f16x8*)(Pc + (size_t)((unsigned)eidx[j + 1] + gb));
    f16x8 v2 = *(const f16x8*)(Pc + (size_t)((unsigned)eidx[j + 2] + gb));
    f16x8 v3 = *(const f16x8*)(Pc + (size_t)((unsigned)eidx[j + 3] + gb));
    f16x8 s = (v0 + v1) + (v2 + v3);
#pragma unroll
    for (int c = 0; c < 8; ++c) acc[c] += (float)s[c];
  }
  for (; j < s1; ++j) {
    f16x8 v = *(const f16x8*)(Pc + (size_t)((unsigned)eidx[j] + gb));
#pragma unroll
    for (int c = 0; c < 8; ++c) acc[c] += (float)v[c];
  }
  f16x8 q = *(const f16x8*)&Q[(size_t)a * 128 + g];
  float inv = 1.0f / fmaxf((float)(s1 - s0), 1.0f);
  f16 outv[8];
#pragma unroll
  for (int u = 0; u < 8; ++u) {
    float v = acc[u] * inv + bias[g + u] + (float)q[u];
    outv[u] = (f16)fmaxf(v, 0.0f);
  }
  *(f16x8*)&ax[(size_t)a * 256 + 128 + g] = *(const f16x8*)outv;
}

// ---------------- layers 2-3 aggregation: agg half <- mean_j x[src_j] ----------------
__global__ __launch_bounds__(256) void gather_mean(
    f16* __restrict__ axb, f16* __restrict__ axa,
    const int* __restrict__ rowptr, const int* __restrict__ eidx) {
  f16* ax = blockIdx.y ? axa : axb;
  const char* axc = (const char*)ax;
  const int t = threadIdx.x;
  const int a = blockIdx.x * 16 + (t >> 4);
  const int g = (t & 15) * 8;
  const unsigned gb = 256u + (unsigned)(t & 15) * 16;
  const int s0 = rowptr[a], s1 = rowptr[a + 1];
  float acc[8];
#pragma unroll
  for (int u = 0; u < 8; ++u) acc[u] = 0.f;
  int j = s0;
  for (; j + 8 <= s1; j += 8) {
    f16x8 v[8];
#pragma unroll
    for (int u = 0; u < 8; ++u)
      v[u] = *(const f16x8*)(axc + (size_t)(((unsigned)eidx[j + u] << 1) + gb));
    f16x8 s = ((v[0] + v[1]) + (v[2] + v[3])) + ((v[4] + v[5]) + (v[6] + v[7]));
#pragma unroll
    for (int c = 0; c < 8; ++c) acc[c] += (float)s[c];
  }
  for (; j + 4 <= s1; j += 4) {
    f16x8 v0 = *(const f16x8*)(axc + (size_t)(((unsigned)eidx[j] << 1) + gb));
    f16x8 v1 = *(const f16x8*)(axc + (size_t)(((unsigned)eidx[j + 1] << 1) + gb));
    f16x8 v2 = *(const f16x8*)(axc + (size_t)(((unsigned)eidx[j + 2] << 1) + gb));
    f16x8 v3 = *(const f16x8*)(axc + (size_t)(((unsigned)eidx[j + 3] << 1) + gb));
    f16x8 s = (v0 + v1) + (v2 + v3);
#pragma unroll
    for (int c = 0; c < 8; ++c) acc[c] += (float)s[c];
  }
  for (; j < s1; ++j) {
    f16x8 v = *(const f16x8*)(axc + (size_t)(((unsigned)eidx[j] << 1) + gb));
#pragma unroll
    for (int c = 0; c < 8; ++c) acc[c] += (float)v[c];
  }
  float inv = 1.0f / fmaxf((float)(s1 - s0), 1.0f);
  f16 outv[8];
#pragma unroll
  for (int u = 0; u < 8; ++u) outv[u] = (f16)(acc[u] * inv);
  *(f16x8*)&ax[(size_t)a * 256 + g] = *(const f16x8*)outv;
}

// ---------------- head: pool -> mlp -> mlp -> fc ----------------
__global__ __launch_bounds__(256) void head_kernel(
    const f16* __restrict__ axb, const f16* __restrict__ axa,
    const int* __restrict__ crys, const float* __restrict__ W_mlp,
    const float* __restrict__ b_mlp, const float* __restrict__ W_fc,
    const float* __restrict__ b_fc, float* __restrict__ outp) {
  __shared__ float sh0[256], sh1[256];
  const int cry = blockIdx.x, c = threadIdx.x;
  const int s = crys[2 * cry], e = crys[2 * cry + 1];
  const f16* src = (c < 128) ? axb : axa;
  const int ch = c & 127;
  float sum = 0.f;
  for (int r = s; r < e; ++r) sum += (float)src[(size_t)r * 256 + 128 + ch];
  sh0[c] = sum / fmaxf((float)(e - s), 1.0f);
  __syncthreads();
  {
    const float* wrow = W_mlp + (size_t)c * 256;
    float s2 = b_mlp[c];
#pragma unroll 8
    for (int k = 0; k < 256; k += 4) {
      float4 w = *(const float4*)&wrow[k];
      s2 += sh0[k] * w.x + sh0[k + 1] * w.y + sh0[k + 2] * w.z + sh0[k + 3] * w.w;
    }
    sh1[c] = s2;
  }
  __syncthreads();
  {
    const float* wrow = W_mlp + 65536 + (size_t)c * 256;
    float s2 = b_mlp[256 + c];
#pragma unroll 8
    for (int k = 0; k < 256; k += 4) {
      float4 w = *(const float4*)&wrow[k];
      s2 += sh1[k] * w.x + sh1[k + 1] * w.y + sh1[k + 2] * w.z + sh1[k + 3] * w.w;
    }
    sh0[c] = s2;
  }
  __syncthreads();
  if (c < 2) {
    const float* wrow = W_fc + c * 256;
    float s2 = b_fc[c];
    for (int k = 0; k < 256; ++k) s2 += sh0[k] * wrow[k];
    outp[cry * 2 + c] = s2;
  }
}

extern "C" void kernel_launch(void* const* d_in, const int* in_sizes, int n_in,
                              void* d_out, int out_size, void* d_ws, size_t ws_size,
                              hipStream_t stream) {
  const float* bond  = (const float*)d_in[0];
  const float* angle = (const float*)d_in[1];
  const int*   nbr   = (const int*)d_in[3];
  const int*   crys  = (const int*)d_in[4];
  const float* Wl_b1 = (const float*)d_in[5];
  const float* Wr_b1 = (const float*)d_in[6];
  const float* b_b1  = (const float*)d_in[7];
  const float* Wl_a1 = (const float*)d_in[8];
  const float* Wr_a1 = (const float*)d_in[9];
  const float* b_a1  = (const float*)d_in[10];
  const float* Wl_b  = (const float*)d_in[11];
  const float* Wr_b  = (const float*)d_in[12];
  const float* b_b   = (const float*)d_in[13];
  const float* Wl_a  = (const float*)d_in[14];
  const float* Wr_a  = (const float*)d_in[15];
  const float* b_a   = (const float*)d_in[16];
  const float* W_mlp = (const float*)d_in[17];
  const float* b_mlp = (const float*)d_in[18];
  const float* W_fc  = (const float*)d_in[19];
  const float* b_fc  = (const float*)d_in[20];

  char* w = (char*)d_ws;
  auto alloc = [&](size_t bytes) {
    void* p = (void*)w;
    w += (bytes + 255) & ~(size_t)255;
    return p;
  };
  f16* axb = (f16*)alloc((size_t)N_ATOMS * 256 * 2);
  f16* axa = (f16*)alloc((size_t)N_ATOMS * 256 * 2);
  f16* Pb  = (f16*)alloc((size_t)N_ATOMS * 128 * 2);
  f16* Qb  = (f16*)alloc((size_t)N_ATOMS * 128 * 2);
  f16* Pa  = (f16*)alloc((size_t)N_ATOMS * 128 * 2);
  f16* Qa  = (f16*)alloc((size_t)N_ATOMS * 128 * 2);
  f16* Wb1c = (f16*)alloc((size_t)256 * 480 * 2);
  f16* Wa1c = (f16*)alloc((size_t)256 * 1152 * 2);
  f16* Wsm  = (f16*)alloc((size_t)4 * 128 * 256 * 2);
  // deg+cursor as ONE contiguous block: the single memset must cover BOTH
  // (0xAA re-poison between timed replays otherwise leaves cursor garbage).
  int* deg    = (int*)alloc((size_t)2 * N_ATOMS * 4);
  int* cursor = deg + N_ATOMS;
  int* rowptr = (int*)alloc((size_t)(N_ATOMS + 1) * 4);
  int* eidx   = (int*)alloc((size_t)NEDGE * 4);
  int* bsum   = (int*)alloc(256 * 4);

  // weights -> fp16 (single dispatch)
  const int CVT_TOTAL = 256 * 480 + 256 * 1152 + 4 * 128 * 256;  // 548864
  cvtW_all<<<(CVT_TOTAL + 255) / 256, 256, 0, stream>>>(
      Wl_b1, Wr_b1, Wl_a1, Wr_a1, Wl_b, Wr_b, Wl_a, Wr_a, Wb1c, Wa1c, Wsm);

  // CSR build
  hipMemsetAsync(deg, 0, (size_t)2 * N_ATOMS * 4, stream);
  k_count<<<(NEDGE + 255) / 256, 256, 0, stream>>>(nbr, deg);
  k_scan1<<<NBLK, 256, 0, stream>>>(deg, rowptr, bsum);
  k_scan2<<<1, 256, 0, stream>>>(bsum);
  k_scan3<<<NBLK, 256, 0, stream>>>(rowptr, bsum);
  k_fill<<<(NEDGE + 255) / 256, 256, 0, stream>>>(nbr, rowptr, cursor, eidx);

  const int GT = (N_ATOMS + 255) / 256;  // 196
  const int AG = N_ATOMS / 16;           // 3125

  // layer 1: single dispatch covers angle+bond x both W-halves
  gemm1all<<<dim3(GT, 2, 2), 512, 0, stream>>>(angle, Wa1c, Pa, Qa,
                                               bond, Wb1c, Pb, Qb, N_ATOMS);
  gather_fin1<<<dim3(AG, 2), 256, 0, stream>>>(Pb, Qb, Pa, Qa, rowptr, eidx,
                                               b_b1, b_a1, axb, axa);

  // layers 2-3 (aggregate-then-project, in-place ax)
  for (int l = 0; l < 2; ++l) {
    gather_mean<<<dim3(AG, 2), 256, 0, stream>>>(axb, axa, rowptr, eidx);
    gemmL<<<dim3(GT, 2), 512, 0, stream>>>(axb, axa, Wsm, b_b, b_a, l, N_ATOMS);
  }

  // head
  head_kernel<<<NCRYS, 256, 0, stream>>>(axb, axa, crys, W_mlp, b_mlp, W_fc, b_fc,
                                         (float*)d_out);
}